// Round 7
// baseline (158.552 us; speedup 1.0000x reference)
//
#include <hip/hip_runtime.h>
#include <math.h>

// Problem constants: B=8, C=256, CR=32, N=4096 (=64*64)
#define B_ 8
#define C_ 256
#define CR_ 32
#define N_ 4096
#define KSPLIT 8   // flash KV splits

typedef __attribute__((ext_vector_type(8))) short bf16x8;   // MFMA A/B frag
typedef __attribute__((ext_vector_type(4))) short bf16x4;
typedef __attribute__((ext_vector_type(4))) float f32x4;    // 16x16 C/D frag
typedef __attribute__((ext_vector_type(16))) float f32x16;  // 32x32 C/D frag

__device__ inline short f2bf(float f) {  // RTNE
  union { float f; unsigned u; } v; v.f = f;
  unsigned r = v.u + 0x7FFFu + ((v.u >> 16) & 1u);
  return (short)(r >> 16);
}
__device__ inline float bf2f(short h) {
  union { unsigned u; float f; } v; v.u = ((unsigned)(unsigned short)h) << 16;
  return v.f;
}
__device__ inline short f2bf_r(float f) {  // cheap round for hot paths
  return (short)((__float_as_uint(f) + 0x8000u) >> 16);
}

// ---------------------------------------------------------------------------
// Kernel 0: weight prep.  WtHi/WtLo = split-bf16 of Wt (log2e folded into Q
// rows 32..63).  WoB = bf16(Wo * scale).
// ---------------------------------------------------------------------------
__global__ __launch_bounds__(256) void prep_weights(const float* __restrict__ Wt,
                                                    const float* __restrict__ Wo,
                                                    const float* __restrict__ scale,
                                                    short* __restrict__ WtHi,
                                                    short* __restrict__ WtLo,
                                                    short* __restrict__ WoB) {
  const int blk = blockIdx.x, tid = threadIdx.x;
  if (blk < 96) {
    float v = Wt[blk * C_ + tid];
    if (blk >= 32 && blk < 64) v *= 1.44269504f;  // log2(e) into Q
    const short h = f2bf(v);
    WtHi[blk * C_ + tid] = h;
    WtLo[blk * C_ + tid] = f2bf(v - bf2f(h));
  } else {
    const int idx = (blk - 96) * 256 + tid;
    WoB[idx] = f2bf(Wo[idx] * scale[0]);
  }
}

// ---------------------------------------------------------------------------
// Kernel 1: QKV projection, split-C 2-way across wave pairs.
// Block = 4 waves: wave = (pair = n-tile, chalf = C-half of 128 channels).
// Each wave: 4 chunks of 32 c, 18 MFMAs/chunk.  Odd waves dump acc to LDS;
// even waves add and run the store epilogue.  Grid 128 x 8 -> 4096 waves.
//   t_tr[b][n][0..31]=K, [32..63]=Q*log2e (bf16);  Vg[b][c][n]=V (bf16)
// ---------------------------------------------------------------------------
__global__ __launch_bounds__(256) void qkv_mfma(const float* __restrict__ x,
                                                const short* __restrict__ WtHi,
                                                const short* __restrict__ WtLo,
                                                short* __restrict__ t_tr,
                                                short* __restrict__ Vg) {
  const int b = blockIdx.y;
  const int tid = threadIdx.x;
  const int wave = tid >> 6, lane = tid & 63;
  const int pair = wave >> 1, chalf = wave & 1;
  const int col = lane & 15, quad = lane >> 4;
  const int n0 = (blockIdx.x * 2 + pair) * 16;
  const int cbase = chalf * 128;

  __shared__ float Ms[2][64][25];  // padded: stride 25 is conflict-free

  const f32x4 z4 = {0.f, 0.f, 0.f, 0.f};
  f32x4 acc[6] = {z4, z4, z4, z4, z4, z4};  // 0..3 = KQ o-tiles, 4..5 = V

  const float* xb = x + (size_t)b * C_ * N_ + n0 + col;
  float xcur[8], xnxt[8];
#pragma unroll
  for (int j = 0; j < 8; ++j) xcur[j] = xb[(size_t)(cbase + quad * 8 + j) * N_];

#pragma unroll
  for (int c0 = cbase; c0 < cbase + 128; c0 += 32) {
    if (c0 < cbase + 96) {
#pragma unroll
      for (int j = 0; j < 8; ++j)
        xnxt[j] = xb[(size_t)(c0 + 32 + quad * 8 + j) * N_];
    }
    bf16x8 xh, xl;
#pragma unroll
    for (int j = 0; j < 8; ++j) {
      const short h = (short)(__float_as_uint(xcur[j]) >> 16);  // trunc hi
      xh[j] = h;
      xl[j] = f2bf_r(xcur[j] - bf2f(h));
    }
#pragma unroll
    for (int ot = 0; ot < 4; ++ot) {  // K/Q: B-operand = Wt rows 0..63
      const int off = (ot * 16 + col) * C_ + c0 + quad * 8;
      const bf16x8 bh = *(const bf16x8*)(WtHi + off);
      const bf16x8 bl = *(const bf16x8*)(WtLo + off);
      acc[ot] = __builtin_amdgcn_mfma_f32_16x16x32_bf16(xh, bh, acc[ot], 0, 0, 0);
      acc[ot] = __builtin_amdgcn_mfma_f32_16x16x32_bf16(xl, bh, acc[ot], 0, 0, 0);
      acc[ot] = __builtin_amdgcn_mfma_f32_16x16x32_bf16(xh, bl, acc[ot], 0, 0, 0);
    }
#pragma unroll
    for (int ct = 0; ct < 2; ++ct) {  // V: A-operand = Wt rows 64..95
      const int off = ((64 + ct * 16) + col) * C_ + c0 + quad * 8;
      const bf16x8 ah = *(const bf16x8*)(WtHi + off);
      const bf16x8 al = *(const bf16x8*)(WtLo + off);
      acc[4 + ct] = __builtin_amdgcn_mfma_f32_16x16x32_bf16(ah, xh, acc[4 + ct], 0, 0, 0);
      acc[4 + ct] = __builtin_amdgcn_mfma_f32_16x16x32_bf16(ah, xl, acc[4 + ct], 0, 0, 0);
      acc[4 + ct] = __builtin_amdgcn_mfma_f32_16x16x32_bf16(al, xh, acc[4 + ct], 0, 0, 0);
    }
#pragma unroll
    for (int j = 0; j < 8; ++j) xcur[j] = xnxt[j];
  }

  // ---- cross-wave C-merge ----
  if (chalf) {
    float* dst = &Ms[pair][lane][0];
#pragma unroll
    for (int t = 0; t < 6; ++t)
#pragma unroll
      for (int r = 0; r < 4; ++r) dst[t * 4 + r] = acc[t][r];
  }
  __syncthreads();
  if (!chalf) {
    const float* src = &Ms[pair][lane][0];
#pragma unroll
    for (int t = 0; t < 6; ++t)
#pragma unroll
      for (int r = 0; r < 4; ++r) acc[t][r] += src[t * 4 + r];
    // K/Q epilogue: D[n][o]
#pragma unroll
    for (int ot = 0; ot < 4; ++ot)
#pragma unroll
      for (int r = 0; r < 4; ++r)
        t_tr[((size_t)b * N_ + n0 + quad * 4 + r) * 64 + ot * 16 + col] =
            f2bf(acc[ot][r]);
    // V epilogue: D[c][n]
#pragma unroll
    for (int ct = 0; ct < 2; ++ct)
#pragma unroll
      for (int r = 0; r < 4; ++r)
        Vg[(size_t)b * CR_ * N_ + (size_t)(ct * 16 + quad * 4 + r) * N_ + n0 + col] =
            f2bf(acc[4 + ct][r]);
  }
}

// ---------------------------------------------------------------------------
// Kernel 2: 32x32-MFMA flash attention, zero LDS, in-register P transform.
// Wave = 64 query cols x one KV-eighth (512 keys in 8 tiles of 64).
// Grid (64 jb, 8 eighths, 8 b) = 4096 single-wave blocks (16 waves/CU).
// kf prefetched one tile ahead; vf loaded at iteration top (consumed late).
// ---------------------------------------------------------------------------
__global__ __launch_bounds__(64, 3) void flash_attn(const short* __restrict__ t_tr,
                                                    const short* __restrict__ Vg,
                                                    short* __restrict__ OPart,
                                                    float* __restrict__ LPart) {
  const int b = blockIdx.z, hq = blockIdx.y;
  const int j0 = blockIdx.x * 64;
  const int lane = threadIdx.x;
  const int j32 = lane & 31, h32 = lane >> 5;
  const short* T = t_tr + (size_t)b * N_ * 64;
  const short* V = Vg + (size_t)b * CR_ * N_;

  const f32x16 z16 = {0.f};
  bf16x8 qf[2][2];  // loop-invariant Q B-frags
#pragma unroll
  for (int jt = 0; jt < 2; ++jt)
#pragma unroll
    for (int ch = 0; ch < 2; ++ch)
      qf[jt][ch] = *(const bf16x8*)(T + (size_t)(j0 + jt * 32 + j32) * 64 + 32 +
                                    ch * 16 + h32 * 8);

  f32x16 acc[2] = {z16, z16};
  float ps[2] = {0.f, 0.f};

  const int ibase = hq * (N_ / KSPLIT);  // 512-key slice
  int i0 = ibase;
  bf16x8 kf[4], kfn[4];
#pragma unroll
  for (int it = 0; it < 2; ++it)
#pragma unroll
    for (int ch = 0; ch < 2; ++ch)
      kf[it * 2 + ch] = *(const bf16x8*)(T + (size_t)(ibase + it * 32 + j32) * 64 +
                                         ch * 16 + h32 * 8);

  for (int iter = 0; iter < 8; ++iter) {
    const int inx = ibase + ((iter + 1) & 7) * 64;  // wraps harmlessly at end
    // V frags for the CURRENT tile (consumed after softmax -> self-hiding)
    bf16x8 vf[4];
#pragma unroll
    for (int ich = 0; ich < 4; ++ich)
      vf[ich] = *(const bf16x8*)(V + (size_t)j32 * N_ + i0 + ich * 16 + h32 * 8);
    // K frags for the NEXT tile
#pragma unroll
    for (int it = 0; it < 2; ++it)
#pragma unroll
      for (int ch = 0; ch < 2; ++ch)
        kfn[it * 2 + ch] = *(const bf16x8*)(T + (size_t)(inx + it * 32 + j32) * 64 +
                                            ch * 16 + h32 * 8);

#pragma unroll
    for (int it = 0; it < 2; ++it) {
#pragma unroll
      for (int jt = 0; jt < 2; ++jt) {
        // ---- S tile (32 i x 32 j), k=32 over two chunks ----
        f32x16 s = __builtin_amdgcn_mfma_f32_32x32x16_bf16(kf[it * 2 + 0], qf[jt][0], z16, 0, 0, 0);
        s = __builtin_amdgcn_mfma_f32_32x32x16_bf16(kf[it * 2 + 1], qf[jt][1], s, 0, 0, 0);
        // ---- p = exp2(s); l tree; pack row-pairs into dwords ----
        float p[16];
#pragma unroll
        for (int r = 0; r < 16; ++r) p[r] = __builtin_amdgcn_exp2f(s[r]);
        ps[jt] += (((p[0] + p[1]) + (p[2] + p[3])) + ((p[4] + p[5]) + (p[6] + p[7]))) +
                  (((p[8] + p[9]) + (p[10] + p[11])) + ((p[12] + p[13]) + (p[14] + p[15])));
        unsigned d[8], xw[8];
#pragma unroll
        for (int k = 0; k < 8; ++k) {
          const unsigned u0 = __float_as_uint(p[2 * k]) + 0x8000u;
          const unsigned u1 = __float_as_uint(p[2 * k + 1]) + 0x8000u;
          d[k] = __builtin_amdgcn_perm(u1, u0, 0x07060302u);  // odd<<16 | even
        }
#pragma unroll
        for (int k = 0; k < 8; ++k) xw[k] = __shfl_xor((int)d[k], 32);
        // ---- B-frags for PV: rows [8*h32, 8*h32+8) of each 16-row chunk ----
        union { unsigned u[4]; bf16x8 v; } f0, f1;
        f0.u[0] = h32 ? xw[2] : d[0];
        f0.u[1] = h32 ? xw[3] : d[1];
        f0.u[2] = h32 ? d[2] : xw[0];
        f0.u[3] = h32 ? d[3] : xw[1];
        f1.u[0] = h32 ? xw[6] : d[4];
        f1.u[1] = h32 ? xw[7] : d[5];
        f1.u[2] = h32 ? d[6] : xw[4];
        f1.u[3] = h32 ? d[7] : xw[5];
        // ---- O += V @ P ----
        acc[jt] = __builtin_amdgcn_mfma_f32_32x32x16_bf16(vf[it * 2 + 0], f0.v, acc[jt], 0, 0, 0);
        acc[jt] = __builtin_amdgcn_mfma_f32_32x32x16_bf16(vf[it * 2 + 1], f1.v, acc[jt], 0, 0, 0);
      }
    }
    i0 = inx;
#pragma unroll
    for (int k = 0; k < 4; ++k) kf[k] = kfn[k];
  }

  // ---- epilogue: finish l across halves, write O/l partials ----
  const size_t base = ((size_t)b * KSPLIT + hq) * N_;
#pragma unroll
  for (int jt = 0; jt < 2; ++jt) {
    const float l = ps[jt] + __shfl_xor(ps[jt], 32);
    const int jg = j0 + jt * 32 + j32;
    if (h32 == 0) LPart[base + jg] = l;
    short* OP = OPart + (base + jg) * 32;
#pragma unroll
    for (int g = 0; g < 4; ++g) {  // regs 4g..4g+3 -> c = 8g + 4*h32 + 0..3
      bf16x4 o = {f2bf(acc[jt][4 * g + 0]), f2bf(acc[jt][4 * g + 1]),
                  f2bf(acc[jt][4 * g + 2]), f2bf(acc[jt][4 * g + 3])};
      *(bf16x4*)(OP + 8 * g + 4 * h32) = o;
    }
  }
}

// ---------------------------------------------------------------------------
// Kernel 3: merge KSPLIT partials, normalize, out-proj, residual.
// Grid (64 n-blocks, 2 co-halves, 8 b) = 1024 blocks (16 waves/CU).
// x prefetched as float4; D-tiles transposed through ping-pong LDS so x/out
// use dwordx4 (global instrs per lane: 64 scalar -> 16 vector).
// ---------------------------------------------------------------------------
__global__ __launch_bounds__(256) void out_proj(const short* __restrict__ OPart,
                                                const float* __restrict__ LPart,
                                                const short* __restrict__ WoB,
                                                const float* __restrict__ x,
                                                float* __restrict__ out) {
  const int b = blockIdx.z, chalf = blockIdx.y;
  const int tid = threadIdx.x;
  const int wave = tid >> 6, lane = tid & 63;
  const int col = lane & 15, quad = lane >> 4;
  const int n0 = blockIdx.x * 64 + wave * 16;
  const int jg = n0 + col;
  const int coL = lane >> 2, n4 = lane & 3;  // transposed-epilogue mapping

  __shared__ float Ls[4][2][16][20];  // [wave][pingpong][co][n+pad]

  // ---- merge partials ----
  float osum[8];
#pragma unroll
  for (int e = 0; e < 8; ++e) osum[e] = 0.f;
  float lsum = 0.f;
#pragma unroll
  for (int h = 0; h < KSPLIT; ++h) {
    const size_t p = ((size_t)b * KSPLIT + h) * N_ + jg;
    const bf16x8 o = *(const bf16x8*)(OPart + p * 32 + quad * 8);
#pragma unroll
    for (int e = 0; e < 8; ++e) osum[e] += bf2f(o[e]);
    lsum += LPart[p];
  }
  const float linv = 1.f / lsum;
  bf16x8 bf;
#pragma unroll
  for (int e = 0; e < 8; ++e) bf[e] = f2bf(osum[e] * linv);

  // ---- prefetch x (vectorized, transposed-lane mapping) ----
  const float* xb = x + (size_t)b * C_ * N_;
  float* ob = out + (size_t)b * C_ * N_;
  float4 xv[8];
#pragma unroll
  for (int ct = 0; ct < 8; ++ct) {
    const int ctg = chalf * 8 + ct;
    xv[ct] = *(const float4*)(xb + (size_t)(ctg * 16 + coL) * N_ + n0 + n4 * 4);
  }

  const f32x4 z4 = {0.f, 0.f, 0.f, 0.f};
#pragma unroll
  for (int ct = 0; ct < 8; ++ct) {
    const int ctg = chalf * 8 + ct;
    const bf16x8 af = *(const bf16x8*)(WoB + (ctg * 16 + col) * 32 + quad * 8);
    const f32x4 a = __builtin_amdgcn_mfma_f32_16x16x32_bf16(af, bf, z4, 0, 0, 0);
    float* L = &Ls[wave][ct & 1][0][0];
#pragma unroll
    for (int r = 0; r < 4; ++r) L[(quad * 4 + r) * 20 + col] = a[r];
    const float4 lv = *(const float4*)&Ls[wave][ct & 1][coL][n4 * 4];
    float4 o;
    o.x = lv.x + xv[ct].x;
    o.y = lv.y + xv[ct].y;
    o.z = lv.z + xv[ct].z;
    o.w = lv.w + xv[ct].w;
    *(float4*)(ob + (size_t)(ctg * 16 + coL) * N_ + n0 + n4 * 4) = o;
  }
}

// ---------------------------------------------------------------------------
extern "C" void kernel_launch(void* const* d_in, const int* in_sizes, int n_in,
                              void* d_out, int out_size, void* d_ws,
                              size_t ws_size, hipStream_t stream) {
  const float* x = (const float*)d_in[0];      // [8,256,64,64]
  const float* Wt = (const float*)d_in[1];     // [96,256]
  const float* Wo = (const float*)d_in[2];     // [256,32]
  const float* scale = (const float*)d_in[3];  // [1]
  float* out = (float*)d_out;

  // ws: OPart bf16 [8][8][4096][32] (16.8 MB) | LPart f32 [8][8][4096] (1 MB)
  //   | t_tr bf16 (4.2 MB) | Vg bf16 (2.1 MB) | WtHi | WtLo | WoB
  short* OPart = (short*)d_ws;
  float* LPart = (float*)(OPart + (size_t)B_ * KSPLIT * N_ * 32);
  short* t_tr = (short*)(LPart + (size_t)B_ * KSPLIT * N_);
  short* Vg = t_tr + (size_t)B_ * N_ * 64;
  short* WtHi = Vg + (size_t)B_ * CR_ * N_;
  short* WtLo = WtHi + 96 * C_;
  short* WoB = WtLo + 96 * C_;

  prep_weights<<<dim3(128), 256, 0, stream>>>(Wt, Wo, scale, WtHi, WtLo, WoB);
  qkv_mfma<<<dim3(128, B_), 256, 0, stream>>>(x, WtHi, WtLo, t_tr, Vg);
  flash_attn<<<dim3(64, KSPLIT, B_), 64, 0, stream>>>(t_tr, Vg, OPart, LPart);
  out_proj<<<dim3(64, 2, B_), 256, 0, stream>>>(OPart, LPart, WoB, x, out);
}